// Round 12
// baseline (1071.987 us; speedup 1.0000x reference)
//
#include <hip/hip_runtime.h>
#include <stdint.h>

typedef __bf16 bf16_t;
typedef __bf16 bf16x4 __attribute__((ext_vector_type(4)));
typedef __bf16 bf16x8 __attribute__((ext_vector_type(8)));
typedef float f32x4 __attribute__((ext_vector_type(4)));

#define MFMA(a, b, c) __builtin_amdgcn_mfma_f32_16x16x32_bf16(a, b, c, 0, 0, 0)

// async global->LDS, 16B per lane; LDS dest = wave-uniform base + lane*16
typedef __attribute__((address_space(3))) uint32_t as3_u32;
typedef __attribute__((address_space(1))) uint32_t as1_u32;
__device__ __forceinline__ void gload_lds16(const void* g, void* l) {
  __builtin_amdgcn_global_load_lds((as1_u32*)g, (as3_u32*)l, 16, 0, 0);
}

// ---------------- f32 -> bf16 convert, all inputs fused ----------------
__global__ void cvt_all(const float* __restrict__ x, const float* __restrict__ wq,
                        const float* __restrict__ wk, const float* __restrict__ wv,
                        bf16_t* __restrict__ dst) {
  int i = blockIdx.x * blockDim.x + threadIdx.x;
  if (i >= 2015232) return;
  const float* src; int off;
  if (i < 1572864) { src = x; off = i; }
  else {
    int j = i - 1572864;
    if (j < 147456)      { src = wq; off = j; }
    else if (j < 294912) { src = wk; off = j - 147456; }
    else                 { src = wv; off = j - 294912; }
  }
  const f32x4 v = reinterpret_cast<const f32x4*>(src)[off];
  bf16x4 o = { (bf16_t)v.x, (bf16_t)v.y, (bf16_t)v.z, (bf16_t)v.w };
  reinterpret_cast<bf16x4*>(dst)[i] = o;
}

// ---------------- QKV projection GEMM (R4 structure, unchanged) ----------------
__global__ __launch_bounds__(256)
void qkv_gemm(const bf16_t* __restrict__ X, const bf16_t* __restrict__ Wb,
              const float* __restrict__ bq, const float* __restrict__ bk,
              const float* __restrict__ bv,
              bf16_t* __restrict__ Qo, bf16_t* __restrict__ Ko, bf16_t* __restrict__ Vo)
{
  __shared__ __align__(16) bf16_t smem[17408];  // staging 4x4096; epilogue 128x136
  bf16_t* const sA0 = smem;
  bf16_t* const sA1 = smem + 4096;
  bf16_t* const sB0 = smem + 8192;
  bf16_t* const sB1 = smem + 12288;
  bf16_t* const ep  = smem;

  const int tid = threadIdx.x;
  const int lane = tid & 63, w = tid >> 6;
  const int wr = w >> 1, wc = w & 1;
  const int lq = lane & 15, lg = lane >> 4;
  const int m0 = blockIdx.x * 128;
  const int n0 = blockIdx.y * 128;
  const int z  = blockIdx.z;

  const bf16_t* W = Wb + z * 589824;
  const float* bias = (z == 0) ? bq : (z == 1) ? bk : bv;

  const int arow = wr * 64, brow = wc * 64;
  const int sr = tid >> 2, scc = (tid & 3) * 8;

  const bf16_t* gA = X + (m0 + sr) * 768 + scc;       // +64*768 for j=1
  const bf16_t* gB = W + (n0 + sr) * 768 + scc;
  const int ko = lg * 8;

  f32x4 acc[4][4] = {};

#define STAGE(bufA, bufB, kt)                                            \
  do {                                                                   \
    const int kk_ = (kt) * 32;                                           \
    gload_lds16(gA + kk_,             &bufA[tid * 8]);                   \
    gload_lds16(gA + kk_ + 64 * 768,  &bufA[(tid + 256) * 8]);           \
    gload_lds16(gB + kk_,             &bufB[tid * 8]);                   \
    gload_lds16(gB + kk_ + 64 * 768,  &bufB[(tid + 256) * 8]);           \
  } while (0)

#define COMPUTE(bufA, bufB)                                              \
  do {                                                                   \
    bf16x8 af[4], bfr[4];                                                \
    _Pragma("unroll")                                                    \
    for (int mf = 0; mf < 4; ++mf)                                       \
      af[mf] = *(const bf16x8*)&bufA[(arow + mf * 16 + lq) * 32 + ko];   \
    _Pragma("unroll")                                                    \
    for (int nf = 0; nf < 4; ++nf)                                       \
      bfr[nf] = *(const bf16x8*)&bufB[(brow + nf * 16 + lq) * 32 + ko];  \
    _Pragma("unroll")                                                    \
    for (int mf = 0; mf < 4; ++mf)                                       \
      _Pragma("unroll")                                                  \
      for (int nf = 0; nf < 4; ++nf)                                     \
        acc[mf][nf] = MFMA(af[mf], bfr[nf], acc[mf][nf]);                \
  } while (0)

  STAGE(sA0, sB0, 0);
  for (int kt = 0; kt < 24; kt += 2) {
    __syncthreads();                      // buf0 staged; prior buf1 reads done
    STAGE(sA1, sB1, kt + 1);              // async, drains at next barrier
    COMPUTE(sA0, sB0);
    __syncthreads();                      // buf1 staged; buf0 reads done
    if (kt + 2 < 24) STAGE(sA0, sB0, kt + 2);
    COMPUTE(sA1, sB1);
  }
  __syncthreads();  // last ds_reads done before epilogue overwrites smem

  // ---- epilogue: repack through LDS for coalesced global writes ----
  const int b = m0 >> 10, sq0 = m0 & 1023;

  if (z < 2) {
#pragma unroll
    for (int nf = 0; nf < 4; ++nf) {
      const int c = brow + nf * 16 + lq;
      const float bval = bias[n0 + c];
#pragma unroll
      for (int mf = 0; mf < 4; ++mf)
#pragma unroll
        for (int jr = 0; jr < 4; ++jr)
          ep[(arow + mf * 16 + lg * 4 + jr) * 136 + c] = (bf16_t)(acc[mf][nf][jr] + bval);
    }
    __syncthreads();
    bf16_t* dst = (z == 0) ? Qo : Ko;
#pragma unroll
    for (int nh = 0; nh < 2; ++nh) {
      const int h = (n0 >> 6) + nh;
#pragma unroll
      for (int rp = 0; rp < 2; ++rp) {
        const int r = (tid >> 2) + rp * 64;
        bf16_t* o = dst + ((size_t)(b * 12 + h) * 1024 + sq0 + r) * 64;
        const bf16_t* s = &ep[r * 136 + nh * 64];
#pragma unroll
        for (int i = 0; i < 2; ++i) {
          const int ch = (tid & 3) + i * 4;
          *(bf16x8*)(o + ch * 8) = *(const bf16x8*)(s + ch * 8);
        }
      }
    }
  } else {
    // transposed: ep[c][r] so V^T rows (fixed d, varying s) are contiguous
#pragma unroll
    for (int nf = 0; nf < 4; ++nf) {
      const int c = brow + nf * 16 + lq;
      const float bval = bias[n0 + c];
#pragma unroll
      for (int mf = 0; mf < 4; ++mf) {
        const int r0 = arow + mf * 16 + lg * 4;
        bf16x4 pv = { (bf16_t)(acc[mf][nf][0] + bval), (bf16_t)(acc[mf][nf][1] + bval),
                      (bf16_t)(acc[mf][nf][2] + bval), (bf16_t)(acc[mf][nf][3] + bval) };
        *(bf16x4*)&ep[c * 136 + r0] = pv;
      }
    }
    __syncthreads();
    const int c = tid >> 1;
    const int h = (n0 >> 6) + (c >> 6), dd = c & 63;
    bf16_t* o = Vo + ((size_t)(b * 12 + h) * 64 + dd) * 1024 + sq0;
    const bf16_t* s = &ep[c * 136];
#pragma unroll
    for (int i = 0; i < 8; ++i) {
      const int ch = (tid & 1) + i * 2;
      *(bf16x8*)(o + ch * 8) = *(const bf16x8*)(s + ch * 8);
    }
  }
#undef STAGE
#undef COMPUTE
}

// ---------------- fused attention (R11 v5 structure), MODE-templated probe ----------------
// MODE 0: NT A-store (current). MODE 1: plain A-store. MODE 2: A-store removed.
// grid (96, 32, REP): z slices identical (byte-identical writes) -> counter visibility.
template <int MODE>
__global__ __launch_bounds__(256)
void attn_kernel(const bf16_t* __restrict__ Q, const bf16_t* __restrict__ K,
                 const bf16_t* __restrict__ V, float* __restrict__ out,
                 float* __restrict__ Aout)
{
  __shared__ __align__(16) bf16_t Pl[32 * 1032];  // 32 q-rows x 1024 t (+8 pad)
  __shared__ __align__(16) bf16_t Ql[32 * 72];
  __shared__ float red[4][32];
  __shared__ float inv_s[32];

  const int tid = threadIdx.x, lane = tid & 63, w = tid >> 6;
  const int lq = lane & 15, lg = lane >> 4;
  const int bh = blockIdx.x, q0 = blockIdx.y * 32;

  const bf16_t* Qp = Q + (bh * 1024 + q0) * 64;
  const bf16_t* Kp = K + bh * 1024 * 64;
  const bf16_t* Vt = V + bh * 64 * 1024;

  {  // load Q block 32x64
    const int q = tid >> 3, du = (tid & 7) * 8;
    *(bf16x8*)&Ql[q * 72 + du] = *(const bf16x8*)(Qp + q * 64 + du);
  }
  __syncthreads();

  const float CEXP = 1.4426950408889634f / 27.712812921102035f;  // log2(e)/sqrt(768)

  bf16x8 bqf[2][2];
#pragma unroll
  for (int dh = 0; dh < 2; ++dh)
#pragma unroll
    for (int qf = 0; qf < 2; ++qf)
      bqf[dh][qf] = *(const bf16x8*)&Ql[(qf * 16 + lq) * 72 + dh * 32 + lg * 8];

  float psum0 = 0.f, psum1 = 0.f;

  for (int i = 0; i < 4; ++i) {
    const int t0 = (w + i * 4) * 64;
    bf16x8 af[4][2];
#pragma unroll
    for (int mf = 0; mf < 4; ++mf) {
      const bf16_t* kp = Kp + (t0 + mf * 16 + lq) * 64 + lg * 8;
      af[mf][0] = *(const bf16x8*)(kp);
      af[mf][1] = *(const bf16x8*)(kp + 32);
    }
#pragma unroll
    for (int mf = 0; mf < 4; ++mf) {
#pragma unroll
      for (int qf = 0; qf < 2; ++qf) {
        f32x4 acc = {};
        acc = MFMA(af[mf][0], bqf[0][qf], acc);
        acc = MFMA(af[mf][1], bqf[1][qf], acc);
        float p0 = exp2f(acc[0] * CEXP);
        float p1 = exp2f(acc[1] * CEXP);
        float p2 = exp2f(acc[2] * CEXP);
        float p3 = exp2f(acc[3] * CEXP);
        if (qf == 0) psum0 += p0 + p1 + p2 + p3;
        else         psum1 += p0 + p1 + p2 + p3;
        bf16x4 pv = { (bf16_t)p0, (bf16_t)p1, (bf16_t)p2, (bf16_t)p3 };
        const int q = qf * 16 + lq;
        const int tt = t0 + mf * 16 + lg * 4;
        *(bf16x4*)&Pl[q * 1032 + tt] = pv;
      }
    }
  }

  psum0 += __shfl_xor(psum0, 16); psum0 += __shfl_xor(psum0, 32);
  psum1 += __shfl_xor(psum1, 16); psum1 += __shfl_xor(psum1, 32);
  if (lane < 16) { red[w][lane] = psum0; red[w][16 + lane] = psum1; }
  __syncthreads();
  if (tid < 32)
    inv_s[tid] = 1.0f / (red[0][tid] + red[1][tid] + red[2][tid] + red[3][tid]);
  __syncthreads();

  // ---- phase 2: PV + fused A-store (1 KB contiguous per wave instruction) ----
  const int r8 = 8 * w;
  float* const Ap0 = Aout + ((size_t)bh * 1024 + q0) * 1024;

  f32x4 oacc[2] = {};
  for (int ks = 0; ks < 32; ++ks) {
    const int kc = ks * 32;
    bf16x8 vb = *(const bf16x8*)(Vt + (w * 16 + lq) * 1024 + kc + lg * 8);
#pragma unroll
    for (int mf = 0; mf < 2; ++mf) {
      bf16x8 pa = *(const bf16x8*)&Pl[(mf * 16 + lq) * 1032 + kc + lg * 8];
      oacc[mf] = MFMA(pa, vb, oacc[mf]);
    }
    if (MODE != 2) {
      const int ar = r8 + (ks & 7);        // wave-uniform row
      const int cc = (ks >> 3) * 256;      // wave-uniform 1KB chunk
      const float ainv = inv_s[ar];        // LDS broadcast
      bf16x4 pv = *(const bf16x4*)&Pl[ar * 1032 + cc + lane * 4];
      f32x4 o = { (float)pv[0] * ainv, (float)pv[1] * ainv,
                  (float)pv[2] * ainv, (float)pv[3] * ainv };
      if (MODE == 0)
        __builtin_nontemporal_store(o, (f32x4*)(Ap0 + (size_t)ar * 1024 + cc + lane * 4));
      else
        *(f32x4*)(Ap0 + (size_t)ar * 1024 + cc + lane * 4) = o;
    }
  }

  // ---- epilogue: out via LDS repack -> 256B contiguous per row ----
  __syncthreads();                       // all Pl reads complete
  float* const Ol = (float*)Pl;          // reuse as [32][68] f32 (8.7 KB)
#pragma unroll
  for (int mf = 0; mf < 2; ++mf)
#pragma unroll
    for (int jr = 0; jr < 4; ++jr) {
      const int q = mf * 16 + lg * 4 + jr;
      Ol[q * 68 + w * 16 + lq] = oacc[mf][jr] * inv_s[q];
    }
  __syncthreads();
  {
    const int b = bh / 12, h = bh % 12;
    const int r = tid >> 3, cchunk = (tid & 7) * 8;
    float* op = out + ((size_t)b * 1024 + q0 + r) * 768 + h * 64 + cchunk;
    f32x4 o0 = *(const f32x4*)&Ol[r * 68 + cchunk];
    f32x4 o1 = *(const f32x4*)&Ol[r * 68 + cchunk + 4];
    *(f32x4*)(op)     = o0;
    *(f32x4*)(op + 4) = o1;
  }
}

extern "C" void kernel_launch(void* const* d_in, const int* in_sizes, int n_in,
                              void* d_out, int out_size, void* d_ws, size_t ws_size,
                              hipStream_t stream) {
  (void)in_sizes; (void)n_in; (void)out_size; (void)ws_size;
  const float* x  = (const float*)d_in[0];
  const float* Wq = (const float*)d_in[1];
  const float* bq = (const float*)d_in[2];
  const float* Wk = (const float*)d_in[3];
  const float* bk = (const float*)d_in[4];
  const float* Wv = (const float*)d_in[5];
  const float* bv = (const float*)d_in[6];

  float* out  = (float*)d_out;
  float* Aout = out + 6291456;  // out [8,1024,768]; A follows

  // workspace (bf16 elements): x_bf | wq|wk|wv | q | k | v^T
  bf16_t* ws   = (bf16_t*)d_ws;
  bf16_t* x_bf = ws;
  bf16_t* w_bf = ws + 6291456;
  bf16_t* q_ws = ws + 8060928;
  bf16_t* k_ws = ws + 14352384;
  bf16_t* v_ws = ws + 20643840;

  cvt_all<<<7872, 256, 0, stream>>>(x, Wq, Wk, Wv, ws);
  qkv_gemm<<<dim3(64, 6, 3), 256, 0, stream>>>(x_bf, w_bf, bq, bk, bv, q_ws, k_ws, v_ws);
  // SACRIFICIAL A/B ROUND (each x3-replicated for counter visibility; all
  // variants write byte-identical data where they write at all; final state
  // is fully written by the PLAIN pass -> deterministic & correct):
  attn_kernel<0><<<dim3(96, 32, 3), 256, 0, stream>>>(q_ws, k_ws, v_ws, out, Aout);  // NT
  attn_kernel<1><<<dim3(96, 32, 3), 256, 0, stream>>>(q_ws, k_ws, v_ws, out, Aout);  // plain
  attn_kernel<2><<<dim3(96, 32, 3), 256, 0, stream>>>(q_ws, k_ws, v_ws, out, Aout);  // no A-store
}

// Round 13
// 207.081 us; speedup vs baseline: 5.1767x; 5.1767x over previous
//
#include <hip/hip_runtime.h>
#include <stdint.h>

typedef __bf16 bf16_t;
typedef __bf16 bf16x4 __attribute__((ext_vector_type(4)));
typedef __bf16 bf16x8 __attribute__((ext_vector_type(8)));
typedef float f32x4 __attribute__((ext_vector_type(4)));

#define MFMA(a, b, c) __builtin_amdgcn_mfma_f32_16x16x32_bf16(a, b, c, 0, 0, 0)

// async global->LDS, 16B per lane; LDS dest = wave-uniform base + lane*16
typedef __attribute__((address_space(3))) uint32_t as3_u32;
typedef __attribute__((address_space(1))) uint32_t as1_u32;
__device__ __forceinline__ void gload_lds16(const void* g, void* l) {
  __builtin_amdgcn_global_load_lds((as1_u32*)g, (as3_u32*)l, 16, 0, 0);
}

// ---------------- f32 -> bf16 convert, all inputs fused ----------------
__global__ void cvt_all(const float* __restrict__ x, const float* __restrict__ wq,
                        const float* __restrict__ wk, const float* __restrict__ wv,
                        bf16_t* __restrict__ dst) {
  int i = blockIdx.x * blockDim.x + threadIdx.x;
  if (i >= 2015232) return;
  const float* src; int off;
  if (i < 1572864) { src = x; off = i; }
  else {
    int j = i - 1572864;
    if (j < 147456)      { src = wq; off = j; }
    else if (j < 294912) { src = wk; off = j - 147456; }
    else                 { src = wv; off = j - 294912; }
  }
  const f32x4 v = reinterpret_cast<const f32x4*>(src)[off];
  bf16x4 o = { (bf16_t)v.x, (bf16_t)v.y, (bf16_t)v.z, (bf16_t)v.w };
  reinterpret_cast<bf16x4*>(dst)[i] = o;
}

// ---------------- QKV projection GEMM (R4 structure, unchanged) ----------------
__global__ __launch_bounds__(256)
void qkv_gemm(const bf16_t* __restrict__ X, const bf16_t* __restrict__ Wb,
              const float* __restrict__ bq, const float* __restrict__ bk,
              const float* __restrict__ bv,
              bf16_t* __restrict__ Qo, bf16_t* __restrict__ Ko, bf16_t* __restrict__ Vo)
{
  __shared__ __align__(16) bf16_t smem[17408];  // staging 4x4096; epilogue 128x136
  bf16_t* const sA0 = smem;
  bf16_t* const sA1 = smem + 4096;
  bf16_t* const sB0 = smem + 8192;
  bf16_t* const sB1 = smem + 12288;
  bf16_t* const ep  = smem;

  const int tid = threadIdx.x;
  const int lane = tid & 63, w = tid >> 6;
  const int wr = w >> 1, wc = w & 1;
  const int lq = lane & 15, lg = lane >> 4;
  const int m0 = blockIdx.x * 128;
  const int n0 = blockIdx.y * 128;
  const int z  = blockIdx.z;

  const bf16_t* W = Wb + z * 589824;
  const float* bias = (z == 0) ? bq : (z == 1) ? bk : bv;

  const int arow = wr * 64, brow = wc * 64;
  const int sr = tid >> 2, scc = (tid & 3) * 8;

  const bf16_t* gA = X + (m0 + sr) * 768 + scc;       // +64*768 for j=1
  const bf16_t* gB = W + (n0 + sr) * 768 + scc;
  const int ko = lg * 8;

  f32x4 acc[4][4] = {};

#define STAGE(bufA, bufB, kt)                                            \
  do {                                                                   \
    const int kk_ = (kt) * 32;                                           \
    gload_lds16(gA + kk_,             &bufA[tid * 8]);                   \
    gload_lds16(gA + kk_ + 64 * 768,  &bufA[(tid + 256) * 8]);           \
    gload_lds16(gB + kk_,             &bufB[tid * 8]);                   \
    gload_lds16(gB + kk_ + 64 * 768,  &bufB[(tid + 256) * 8]);           \
  } while (0)

#define COMPUTE(bufA, bufB)                                              \
  do {                                                                   \
    bf16x8 af[4], bfr[4];                                                \
    _Pragma("unroll")                                                    \
    for (int mf = 0; mf < 4; ++mf)                                       \
      af[mf] = *(const bf16x8*)&bufA[(arow + mf * 16 + lq) * 32 + ko];   \
    _Pragma("unroll")                                                    \
    for (int nf = 0; nf < 4; ++nf)                                       \
      bfr[nf] = *(const bf16x8*)&bufB[(brow + nf * 16 + lq) * 32 + ko];  \
    _Pragma("unroll")                                                    \
    for (int mf = 0; mf < 4; ++mf)                                       \
      _Pragma("unroll")                                                  \
      for (int nf = 0; nf < 4; ++nf)                                     \
        acc[mf][nf] = MFMA(af[mf], bfr[nf], acc[mf][nf]);                \
  } while (0)

  STAGE(sA0, sB0, 0);
  for (int kt = 0; kt < 24; kt += 2) {
    __syncthreads();                      // buf0 staged; prior buf1 reads done
    STAGE(sA1, sB1, kt + 1);              // async, drains at next barrier
    COMPUTE(sA0, sB0);
    __syncthreads();                      // buf1 staged; buf0 reads done
    if (kt + 2 < 24) STAGE(sA0, sB0, kt + 2);
    COMPUTE(sA1, sB1);
  }
  __syncthreads();  // last ds_reads done before epilogue overwrites smem

  // ---- epilogue: repack through LDS for coalesced global writes ----
  const int b = m0 >> 10, sq0 = m0 & 1023;

  if (z < 2) {
#pragma unroll
    for (int nf = 0; nf < 4; ++nf) {
      const int c = brow + nf * 16 + lq;
      const float bval = bias[n0 + c];
#pragma unroll
      for (int mf = 0; mf < 4; ++mf)
#pragma unroll
        for (int jr = 0; jr < 4; ++jr)
          ep[(arow + mf * 16 + lg * 4 + jr) * 136 + c] = (bf16_t)(acc[mf][nf][jr] + bval);
    }
    __syncthreads();
    bf16_t* dst = (z == 0) ? Qo : Ko;
#pragma unroll
    for (int nh = 0; nh < 2; ++nh) {
      const int h = (n0 >> 6) + nh;
#pragma unroll
      for (int rp = 0; rp < 2; ++rp) {
        const int r = (tid >> 2) + rp * 64;
        bf16_t* o = dst + ((size_t)(b * 12 + h) * 1024 + sq0 + r) * 64;
        const bf16_t* s = &ep[r * 136 + nh * 64];
#pragma unroll
        for (int i = 0; i < 2; ++i) {
          const int ch = (tid & 3) + i * 4;
          *(bf16x8*)(o + ch * 8) = *(const bf16x8*)(s + ch * 8);
        }
      }
    }
  } else {
    // transposed: ep[c][r] so V^T rows (fixed d, varying s) are contiguous
#pragma unroll
    for (int nf = 0; nf < 4; ++nf) {
      const int c = brow + nf * 16 + lq;
      const float bval = bias[n0 + c];
#pragma unroll
      for (int mf = 0; mf < 4; ++mf) {
        const int r0 = arow + mf * 16 + lg * 4;
        bf16x4 pv = { (bf16_t)(acc[mf][nf][0] + bval), (bf16_t)(acc[mf][nf][1] + bval),
                      (bf16_t)(acc[mf][nf][2] + bval), (bf16_t)(acc[mf][nf][3] + bval) };
        *(bf16x4*)&ep[c * 136 + r0] = pv;
      }
    }
    __syncthreads();
    const int c = tid >> 1;
    const int h = (n0 >> 6) + (c >> 6), dd = c & 63;
    bf16_t* o = Vo + ((size_t)(b * 12 + h) * 64 + dd) * 1024 + sq0;
    const bf16_t* s = &ep[c * 136];
#pragma unroll
    for (int i = 0; i < 8; ++i) {
      const int ch = (tid & 1) + i * 2;
      *(bf16x8*)(o + ch * 8) = *(const bf16x8*)(s + ch * 8);
    }
  }
#undef STAGE
#undef COMPUTE
}

// ---------------- fused attention v6: chunk-streamed two-pass, ~23 KB LDS ----------------
// grid (96, 32): x = head (XCD-pinned), y = 32-row q-block. 4 waves.
// Pass 1: QK^T+exp -> row sums only (no P store) -> inv_s[32].
// Pass 2: per 128-t chunk: QK^T -> exp -> *inv (pre-normalized) -> bf16 chunk in
//         double-buffered LDS (1 barrier/chunk) -> coalesced NT A-store + PV MFMA.
// out = sum(P_norm * V) directly (no final scaling).
__global__ __launch_bounds__(256)
void attn_kernel(const bf16_t* __restrict__ Q, const bf16_t* __restrict__ K,
                 const bf16_t* __restrict__ V, float* __restrict__ out,
                 float* __restrict__ Aout)
{
  __shared__ __align__(16) bf16_t Ql[32 * 72];       // 4.6 KB
  __shared__ __align__(16) bf16_t Pc[2][32 * 136];   // 2 x 8.7 KB chunk buffers
  __shared__ float red[4][32];
  __shared__ float inv_s[32];

  const int tid = threadIdx.x, lane = tid & 63, w = tid >> 6;
  const int lq = lane & 15, lg = lane >> 4;
  const int bh = blockIdx.x, q0 = blockIdx.y * 32;

  const bf16_t* Qp = Q + (bh * 1024 + q0) * 64;
  const bf16_t* Kp = K + bh * 1024 * 64;
  const bf16_t* Vt = V + bh * 64 * 1024;

  {  // load Q block 32x64
    const int q = tid >> 3, du = (tid & 7) * 8;
    *(bf16x8*)&Ql[q * 72 + du] = *(const bf16x8*)(Qp + q * 64 + du);
  }
  __syncthreads();

  const float CEXP = 1.4426950408889634f / 27.712812921102035f;  // log2(e)/sqrt(768)

  bf16x8 bqf[2][2];
#pragma unroll
  for (int dh = 0; dh < 2; ++dh)
#pragma unroll
    for (int qf = 0; qf < 2; ++qf)
      bqf[dh][qf] = *(const bf16x8*)&Ql[(qf * 16 + lq) * 72 + dh * 32 + lg * 8];

  // ---- pass 1: row sums only ----
  float psum0 = 0.f, psum1 = 0.f;
  for (int i = 0; i < 4; ++i) {
    const int t0 = (w + i * 4) * 64;
    bf16x8 af[4][2];
#pragma unroll
    for (int mf = 0; mf < 4; ++mf) {
      const bf16_t* kp = Kp + (t0 + mf * 16 + lq) * 64 + lg * 8;
      af[mf][0] = *(const bf16x8*)(kp);
      af[mf][1] = *(const bf16x8*)(kp + 32);
    }
#pragma unroll
    for (int mf = 0; mf < 4; ++mf) {
#pragma unroll
      for (int qf = 0; qf < 2; ++qf) {
        f32x4 acc = {};
        acc = MFMA(af[mf][0], bqf[0][qf], acc);
        acc = MFMA(af[mf][1], bqf[1][qf], acc);
        float s = exp2f(acc[0] * CEXP) + exp2f(acc[1] * CEXP)
                + exp2f(acc[2] * CEXP) + exp2f(acc[3] * CEXP);
        if (qf == 0) psum0 += s; else psum1 += s;
      }
    }
  }

  psum0 += __shfl_xor(psum0, 16); psum0 += __shfl_xor(psum0, 32);
  psum1 += __shfl_xor(psum1, 16); psum1 += __shfl_xor(psum1, 32);
  if (lane < 16) { red[w][lane] = psum0; red[w][16 + lane] = psum1; }
  __syncthreads();
  if (tid < 32)
    inv_s[tid] = 1.0f / (red[0][tid] + red[1][tid] + red[2][tid] + red[3][tid]);
  __syncthreads();

  const float inv0 = inv_s[lq];        // q = lq       (qf=0)
  const float inv1 = inv_s[16 + lq];   // q = 16 + lq  (qf=1)

  // ---- pass 2: chunk-streamed QK^T -> normalized P -> A-store + PV ----
  const int ar = tid >> 3, ac = tid & 7;           // A-store: 8 threads/row
  float* const ApR = Aout + ((size_t)bh * 1024 + q0 + ar) * 1024;
  f32x4 oacc[2] = {};

  for (int c = 0; c < 8; ++c) {
    bf16_t* const buf = Pc[c & 1];
    const int tsub = c * 128 + w * 32;

    // compute 32q x 32t sub-chunk (this wave) -> normalized bf16 into buf
#pragma unroll
    for (int mf = 0; mf < 2; ++mf) {
      const bf16_t* kp = Kp + (tsub + mf * 16 + lq) * 64 + lg * 8;
      bf16x8 a0 = *(const bf16x8*)(kp);
      bf16x8 a1 = *(const bf16x8*)(kp + 32);
#pragma unroll
      for (int qf = 0; qf < 2; ++qf) {
        f32x4 acc = {};
        acc = MFMA(a0, bqf[0][qf], acc);
        acc = MFMA(a1, bqf[1][qf], acc);
        const float inv = (qf == 0) ? inv0 : inv1;
        bf16x4 pv = { (bf16_t)(exp2f(acc[0] * CEXP) * inv),
                      (bf16_t)(exp2f(acc[1] * CEXP) * inv),
                      (bf16_t)(exp2f(acc[2] * CEXP) * inv),
                      (bf16_t)(exp2f(acc[3] * CEXP) * inv) };
        *(bf16x4*)&buf[(qf * 16 + lq) * 136 + w * 32 + mf * 16 + lg * 4] = pv;
      }
    }
    __syncthreads();  // chunk complete; also guarantees buf's prior consumers done

    // A-store: 32 rows x 128 cols fp32, 128B contiguous per row per instruction
    {
      float* const Ap = ApR + c * 128;
      const bf16_t* const ps = &buf[ar * 136];
#pragma unroll
      for (int j = 0; j < 4; ++j) {
        const int col = ac * 4 + j * 32;
        bf16x4 pv = *(const bf16x4*)(ps + col);
        f32x4 o = { (float)pv[0], (float)pv[1], (float)pv[2], (float)pv[3] };
        __builtin_nontemporal_store(o, (f32x4*)(Ap + col));
      }
    }

    // PV: wave w owns d-range [w*16, w*16+16); k = this 128-t chunk
#pragma unroll
    for (int ks = 0; ks < 4; ++ks) {
      bf16x8 vb = *(const bf16x8*)(Vt + (w * 16 + lq) * 1024 + c * 128 + ks * 32 + lg * 8);
#pragma unroll
      for (int mf = 0; mf < 2; ++mf) {
        bf16x8 pa = *(const bf16x8*)&buf[(mf * 16 + lq) * 136 + ks * 32 + lg * 8];
        oacc[mf] = MFMA(pa, vb, oacc[mf]);
      }
    }
  }

  // ---- epilogue: out via LDS repack -> 256B contiguous per row (pre-normalized) ----
  __syncthreads();
  float* const Ol = (float*)Pc;          // reuse chunk buffers: [32][68] f32
#pragma unroll
  for (int mf = 0; mf < 2; ++mf)
#pragma unroll
    for (int jr = 0; jr < 4; ++jr) {
      const int q = mf * 16 + lg * 4 + jr;
      Ol[q * 68 + w * 16 + lq] = oacc[mf][jr];
    }
  __syncthreads();
  {
    const int b = bh / 12, h = bh % 12;
    const int r = tid >> 3, cchunk = (tid & 7) * 8;
    float* op = out + ((size_t)b * 1024 + q0 + r) * 768 + h * 64 + cchunk;
    f32x4 o0 = *(const f32x4*)&Ol[r * 68 + cchunk];
    f32x4 o1 = *(const f32x4*)&Ol[r * 68 + cchunk + 4];
    *(f32x4*)(op)     = o0;
    *(f32x4*)(op + 4) = o1;
  }
}

extern "C" void kernel_launch(void* const* d_in, const int* in_sizes, int n_in,
                              void* d_out, int out_size, void* d_ws, size_t ws_size,
                              hipStream_t stream) {
  (void)in_sizes; (void)n_in; (void)out_size; (void)ws_size;
  const float* x  = (const float*)d_in[0];
  const float* Wq = (const float*)d_in[1];
  const float* bq = (const float*)d_in[2];
  const float* Wk = (const float*)d_in[3];
  const float* bk = (const float*)d_in[4];
  const float* Wv = (const float*)d_in[5];
  const float* bv = (const float*)d_in[6];

  float* out  = (float*)d_out;
  float* Aout = out + 6291456;  // out [8,1024,768]; A follows

  // workspace (bf16 elements): x_bf | wq|wk|wv | q | k | v^T
  bf16_t* ws   = (bf16_t*)d_ws;
  bf16_t* x_bf = ws;
  bf16_t* w_bf = ws + 6291456;
  bf16_t* q_ws = ws + 8060928;
  bf16_t* k_ws = ws + 14352384;
  bf16_t* v_ws = ws + 20643840;

  cvt_all<<<7872, 256, 0, stream>>>(x, Wq, Wk, Wv, ws);
  qkv_gemm<<<dim3(64, 6, 3), 256, 0, stream>>>(x_bf, w_bf, bq, bk, bv, q_ws, k_ws, v_ws);
  attn_kernel<<<dim3(96, 32), 256, 0, stream>>>(q_ws, k_ws, v_ws, out, Aout);
}

// Round 14
// 189.198 us; speedup vs baseline: 5.6660x; 1.0945x over previous
//
#include <hip/hip_runtime.h>
#include <stdint.h>

typedef __bf16 bf16_t;
typedef __bf16 bf16x4 __attribute__((ext_vector_type(4)));
typedef __bf16 bf16x8 __attribute__((ext_vector_type(8)));
typedef float f32x4 __attribute__((ext_vector_type(4)));

#define MFMA(a, b, c) __builtin_amdgcn_mfma_f32_16x16x32_bf16(a, b, c, 0, 0, 0)

// raw v_exp_f32 (inputs bounded here; skips libm guard path)
__device__ __forceinline__ float fexp2(float x) { return __builtin_amdgcn_exp2f(x); }

// async global->LDS, 16B per lane; LDS dest = wave-uniform base + lane*16
typedef __attribute__((address_space(3))) uint32_t as3_u32;
typedef __attribute__((address_space(1))) uint32_t as1_u32;
__device__ __forceinline__ void gload_lds16(const void* g, void* l) {
  __builtin_amdgcn_global_load_lds((as1_u32*)g, (as3_u32*)l, 16, 0, 0);
}

// ---------------- f32 -> bf16 convert, all inputs fused ----------------
__global__ void cvt_all(const float* __restrict__ x, const float* __restrict__ wq,
                        const float* __restrict__ wk, const float* __restrict__ wv,
                        bf16_t* __restrict__ dst) {
  int i = blockIdx.x * blockDim.x + threadIdx.x;
  if (i >= 2015232) return;
  const float* src; int off;
  if (i < 1572864) { src = x; off = i; }
  else {
    int j = i - 1572864;
    if (j < 147456)      { src = wq; off = j; }
    else if (j < 294912) { src = wk; off = j - 147456; }
    else                 { src = wv; off = j - 294912; }
  }
  const f32x4 v = reinterpret_cast<const f32x4*>(src)[off];
  bf16x4 o = { (bf16_t)v.x, (bf16_t)v.y, (bf16_t)v.z, (bf16_t)v.w };
  reinterpret_cast<bf16x4*>(dst)[i] = o;
}

// ---------------- QKV projection GEMM (R4 structure, unchanged) ----------------
__global__ __launch_bounds__(256)
void qkv_gemm(const bf16_t* __restrict__ X, const bf16_t* __restrict__ Wb,
              const float* __restrict__ bq, const float* __restrict__ bk,
              const float* __restrict__ bv,
              bf16_t* __restrict__ Qo, bf16_t* __restrict__ Ko, bf16_t* __restrict__ Vo)
{
  __shared__ __align__(16) bf16_t smem[17408];  // staging 4x4096; epilogue 128x136
  bf16_t* const sA0 = smem;
  bf16_t* const sA1 = smem + 4096;
  bf16_t* const sB0 = smem + 8192;
  bf16_t* const sB1 = smem + 12288;
  bf16_t* const ep  = smem;

  const int tid = threadIdx.x;
  const int lane = tid & 63, w = tid >> 6;
  const int wr = w >> 1, wc = w & 1;
  const int lq = lane & 15, lg = lane >> 4;
  const int m0 = blockIdx.x * 128;
  const int n0 = blockIdx.y * 128;
  const int z  = blockIdx.z;

  const bf16_t* W = Wb + z * 589824;
  const float* bias = (z == 0) ? bq : (z == 1) ? bk : bv;

  const int arow = wr * 64, brow = wc * 64;
  const int sr = tid >> 2, scc = (tid & 3) * 8;

  const bf16_t* gA = X + (m0 + sr) * 768 + scc;       // +64*768 for j=1
  const bf16_t* gB = W + (n0 + sr) * 768 + scc;
  const int ko = lg * 8;

  f32x4 acc[4][4] = {};

#define STAGE(bufA, bufB, kt)                                            \
  do {                                                                   \
    const int kk_ = (kt) * 32;                                           \
    gload_lds16(gA + kk_,             &bufA[tid * 8]);                   \
    gload_lds16(gA + kk_ + 64 * 768,  &bufA[(tid + 256) * 8]);           \
    gload_lds16(gB + kk_,             &bufB[tid * 8]);                   \
    gload_lds16(gB + kk_ + 64 * 768,  &bufB[(tid + 256) * 8]);           \
  } while (0)

#define COMPUTE(bufA, bufB)                                              \
  do {                                                                   \
    bf16x8 af[4], bfr[4];                                                \
    _Pragma("unroll")                                                    \
    for (int mf = 0; mf < 4; ++mf)                                       \
      af[mf] = *(const bf16x8*)&bufA[(arow + mf * 16 + lq) * 32 + ko];   \
    _Pragma("unroll")                                                    \
    for (int nf = 0; nf < 4; ++nf)                                       \
      bfr[nf] = *(const bf16x8*)&bufB[(brow + nf * 16 + lq) * 32 + ko];  \
    _Pragma("unroll")                                                    \
    for (int mf = 0; mf < 4; ++mf)                                       \
      _Pragma("unroll")                                                  \
      for (int nf = 0; nf < 4; ++nf)                                     \
        acc[mf][nf] = MFMA(af[mf], bfr[nf], acc[mf][nf]);                \
  } while (0)

  STAGE(sA0, sB0, 0);
  for (int kt = 0; kt < 24; kt += 2) {
    __syncthreads();                      // buf0 staged; prior buf1 reads done
    STAGE(sA1, sB1, kt + 1);              // async, drains at next barrier
    COMPUTE(sA0, sB0);
    __syncthreads();                      // buf1 staged; buf0 reads done
    if (kt + 2 < 24) STAGE(sA0, sB0, kt + 2);
    COMPUTE(sA1, sB1);
  }
  __syncthreads();  // last ds_reads done before epilogue overwrites smem

  // ---- epilogue: repack through LDS for coalesced global writes ----
  const int b = m0 >> 10, sq0 = m0 & 1023;

  if (z < 2) {
#pragma unroll
    for (int nf = 0; nf < 4; ++nf) {
      const int c = brow + nf * 16 + lq;
      const float bval = bias[n0 + c];
#pragma unroll
      for (int mf = 0; mf < 4; ++mf)
#pragma unroll
        for (int jr = 0; jr < 4; ++jr)
          ep[(arow + mf * 16 + lg * 4 + jr) * 136 + c] = (bf16_t)(acc[mf][nf][jr] + bval);
    }
    __syncthreads();
    bf16_t* dst = (z == 0) ? Qo : Ko;
#pragma unroll
    for (int nh = 0; nh < 2; ++nh) {
      const int h = (n0 >> 6) + nh;
#pragma unroll
      for (int rp = 0; rp < 2; ++rp) {
        const int r = (tid >> 2) + rp * 64;
        bf16_t* o = dst + ((size_t)(b * 12 + h) * 1024 + sq0 + r) * 64;
        const bf16_t* s = &ep[r * 136 + nh * 64];
#pragma unroll
        for (int i = 0; i < 2; ++i) {
          const int ch = (tid & 3) + i * 4;
          *(bf16x8*)(o + ch * 8) = *(const bf16x8*)(s + ch * 8);
        }
      }
    }
  } else {
    // transposed: ep[c][r] so V^T rows (fixed d, varying s) are contiguous
#pragma unroll
    for (int nf = 0; nf < 4; ++nf) {
      const int c = brow + nf * 16 + lq;
      const float bval = bias[n0 + c];
#pragma unroll
      for (int mf = 0; mf < 4; ++mf) {
        const int r0 = arow + mf * 16 + lg * 4;
        bf16x4 pv = { (bf16_t)(acc[mf][nf][0] + bval), (bf16_t)(acc[mf][nf][1] + bval),
                      (bf16_t)(acc[mf][nf][2] + bval), (bf16_t)(acc[mf][nf][3] + bval) };
        *(bf16x4*)&ep[c * 136 + r0] = pv;
      }
    }
    __syncthreads();
    const int c = tid >> 1;
    const int h = (n0 >> 6) + (c >> 6), dd = c & 63;
    bf16_t* o = Vo + ((size_t)(b * 12 + h) * 64 + dd) * 1024 + sq0;
    const bf16_t* s = &ep[c * 136];
#pragma unroll
    for (int i = 0; i < 8; ++i) {
      const int ch = (tid & 1) + i * 2;
      *(bf16x8*)(o + ch * 8) = *(const bf16x8*)(s + ch * 8);
    }
  }
#undef STAGE
#undef COMPUTE
}

// ---------------- fused attention v7: R11 structure + fast exp + deep unrolls ----------------
// grid (96, 32): x = head (XCD-pinned), y = 32-row q-block.
__global__ __launch_bounds__(256)
void attn_kernel(const bf16_t* __restrict__ Q, const bf16_t* __restrict__ K,
                 const bf16_t* __restrict__ V, float* __restrict__ out,
                 float* __restrict__ Aout)
{
  __shared__ __align__(16) bf16_t Pl[32 * 1032];  // 32 q-rows x 1024 t (+8 pad)
  __shared__ __align__(16) bf16_t Ql[32 * 72];
  __shared__ float red[4][32];
  __shared__ float inv_s[32];

  const int tid = threadIdx.x, lane = tid & 63, w = tid >> 6;
  const int lq = lane & 15, lg = lane >> 4;
  const int bh = blockIdx.x, q0 = blockIdx.y * 32;

  const bf16_t* Qp = Q + (bh * 1024 + q0) * 64;
  const bf16_t* Kp = K + bh * 1024 * 64;
  const bf16_t* Vt = V + bh * 64 * 1024;

  {  // load Q block 32x64
    const int q = tid >> 3, du = (tid & 7) * 8;
    *(bf16x8*)&Ql[q * 72 + du] = *(const bf16x8*)(Qp + q * 64 + du);
  }
  __syncthreads();

  const float CEXP = 1.4426950408889634f / 27.712812921102035f;  // log2(e)/sqrt(768)

  bf16x8 bqf[2][2];
#pragma unroll
  for (int dh = 0; dh < 2; ++dh)
#pragma unroll
    for (int qf = 0; qf < 2; ++qf)
      bqf[dh][qf] = *(const bf16x8*)&Ql[(qf * 16 + lq) * 72 + dh * 32 + lg * 8];

  float psum0 = 0.f, psum1 = 0.f;

#pragma unroll 2
  for (int i = 0; i < 4; ++i) {
    const int t0 = (w + i * 4) * 64;
    bf16x8 af[4][2];
#pragma unroll
    for (int mf = 0; mf < 4; ++mf) {
      const bf16_t* kp = Kp + (t0 + mf * 16 + lq) * 64 + lg * 8;
      af[mf][0] = *(const bf16x8*)(kp);
      af[mf][1] = *(const bf16x8*)(kp + 32);
    }
#pragma unroll
    for (int mf = 0; mf < 4; ++mf) {
#pragma unroll
      for (int qf = 0; qf < 2; ++qf) {
        f32x4 acc = {};
        acc = MFMA(af[mf][0], bqf[0][qf], acc);
        acc = MFMA(af[mf][1], bqf[1][qf], acc);
        float p0 = fexp2(acc[0] * CEXP);
        float p1 = fexp2(acc[1] * CEXP);
        float p2 = fexp2(acc[2] * CEXP);
        float p3 = fexp2(acc[3] * CEXP);
        if (qf == 0) psum0 += p0 + p1 + p2 + p3;
        else         psum1 += p0 + p1 + p2 + p3;
        bf16x4 pv = { (bf16_t)p0, (bf16_t)p1, (bf16_t)p2, (bf16_t)p3 };
        const int q = qf * 16 + lq;
        const int tt = t0 + mf * 16 + lg * 4;
        *(bf16x4*)&Pl[q * 1032 + tt] = pv;
      }
    }
  }

  psum0 += __shfl_xor(psum0, 16); psum0 += __shfl_xor(psum0, 32);
  psum1 += __shfl_xor(psum1, 16); psum1 += __shfl_xor(psum1, 32);
  if (lane < 16) { red[w][lane] = psum0; red[w][16 + lane] = psum1; }
  __syncthreads();
  if (tid < 32)
    inv_s[tid] = 1.0f / (red[0][tid] + red[1][tid] + red[2][tid] + red[3][tid]);
  __syncthreads();

  // ---- phase 2: PV + fused A-store (1 KB contiguous per wave instruction) ----
  const int r8 = 8 * w;
  float* const Ap0 = Aout + ((size_t)bh * 1024 + q0) * 1024;

  f32x4 oacc[2] = {};
#pragma unroll 4
  for (int ks = 0; ks < 32; ++ks) {
    const int kc = ks * 32;
    bf16x8 vb = *(const bf16x8*)(Vt + (w * 16 + lq) * 1024 + kc + lg * 8);
#pragma unroll
    for (int mf = 0; mf < 2; ++mf) {
      bf16x8 pa = *(const bf16x8*)&Pl[(mf * 16 + lq) * 1032 + kc + lg * 8];
      oacc[mf] = MFMA(pa, vb, oacc[mf]);
    }
    const int ar = r8 + (ks & 7);        // wave-uniform row
    const int cc = (ks >> 3) * 256;      // wave-uniform 1KB chunk
    const float ainv = inv_s[ar];        // LDS broadcast
    bf16x4 pv = *(const bf16x4*)&Pl[ar * 1032 + cc + lane * 4];
    f32x4 o = { (float)pv[0] * ainv, (float)pv[1] * ainv,
                (float)pv[2] * ainv, (float)pv[3] * ainv };
    __builtin_nontemporal_store(o, (f32x4*)(Ap0 + (size_t)ar * 1024 + cc + lane * 4));
  }

  // ---- epilogue: out via LDS repack -> 256B contiguous per row ----
  __syncthreads();                       // all Pl reads complete
  float* const Ol = (float*)Pl;          // reuse as [32][68] f32 (8.7 KB)
#pragma unroll
  for (int mf = 0; mf < 2; ++mf)
#pragma unroll
    for (int jr = 0; jr < 4; ++jr) {
      const int q = mf * 16 + lg * 4 + jr;
      Ol[q * 68 + w * 16 + lq] = oacc[mf][jr] * inv_s[q];
    }
  __syncthreads();
  {
    const int b = bh / 12, h = bh % 12;
    const int r = tid >> 3, cchunk = (tid & 7) * 8;
    float* op = out + ((size_t)b * 1024 + q0 + r) * 768 + h * 64 + cchunk;
    f32x4 o0 = *(const f32x4*)&Ol[r * 68 + cchunk];
    f32x4 o1 = *(const f32x4*)&Ol[r * 68 + cchunk + 4];
    *(f32x4*)(op)     = o0;
    *(f32x4*)(op + 4) = o1;
  }
}

extern "C" void kernel_launch(void* const* d_in, const int* in_sizes, int n_in,
                              void* d_out, int out_size, void* d_ws, size_t ws_size,
                              hipStream_t stream) {
  (void)in_sizes; (void)n_in; (void)out_size; (void)ws_size;
  const float* x  = (const float*)d_in[0];
  const float* Wq = (const float*)d_in[1];
  const float* bq = (const float*)d_in[2];
  const float* Wk = (const float*)d_in[3];
  const float* bk = (const float*)d_in[4];
  const float* Wv = (const float*)d_in[5];
  const float* bv = (const float*)d_in[6];

  float* out  = (float*)d_out;
  float* Aout = out + 6291456;  // out [8,1024,768]; A follows

  // workspace (bf16 elements): x_bf | wq|wk|wv | q | k | v^T
  bf16_t* ws   = (bf16_t*)d_ws;
  bf16_t* x_bf = ws;
  bf16_t* w_bf = ws + 6291456;
  bf16_t* q_ws = ws + 8060928;
  bf16_t* k_ws = ws + 14352384;
  bf16_t* v_ws = ws + 20643840;

  cvt_all<<<7872, 256, 0, stream>>>(x, Wq, Wk, Wv, ws);
  qkv_gemm<<<dim3(64, 6, 3), 256, 0, stream>>>(x_bf, w_bf, bq, bk, bv, q_ws, k_ws, v_ws);
  attn_kernel<<<dim3(96, 32), 256, 0, stream>>>(q_ws, k_ws, v_ws, out, Aout);
}

// Round 15
// 170.393 us; speedup vs baseline: 6.2913x; 1.1104x over previous
//
#include <hip/hip_runtime.h>
#include <stdint.h>

typedef __bf16 bf16_t;
typedef __bf16 bf16x4 __attribute__((ext_vector_type(4)));
typedef __bf16 bf16x8 __attribute__((ext_vector_type(8)));
typedef float f32x4 __attribute__((ext_vector_type(4)));

#define MFMA(a, b, c) __builtin_amdgcn_mfma_f32_16x16x32_bf16(a, b, c, 0, 0, 0)

// async global->LDS, 16B per lane; LDS dest = wave-uniform base + lane*16
typedef __attribute__((address_space(3))) uint32_t as3_u32;
typedef __attribute__((address_space(1))) uint32_t as1_u32;
__device__ __forceinline__ void gload_lds16(const void* g, void* l) {
  __builtin_amdgcn_global_load_lds((as1_u32*)g, (as3_u32*)l, 16, 0, 0);
}

// ---------------- f32 -> bf16 convert, all inputs fused ----------------
__global__ void cvt_all(const float* __restrict__ x, const float* __restrict__ wq,
                        const float* __restrict__ wk, const float* __restrict__ wv,
                        bf16_t* __restrict__ dst) {
  int i = blockIdx.x * blockDim.x + threadIdx.x;
  if (i >= 2015232) return;
  const float* src; int off;
  if (i < 1572864) { src = x; off = i; }
  else {
    int j = i - 1572864;
    if (j < 147456)      { src = wq; off = j; }
    else if (j < 294912) { src = wk; off = j - 147456; }
    else                 { src = wv; off = j - 294912; }
  }
  const f32x4 v = reinterpret_cast<const f32x4*>(src)[off];
  bf16x4 o = { (bf16_t)v.x, (bf16_t)v.y, (bf16_t)v.z, (bf16_t)v.w };
  reinterpret_cast<bf16x4*>(dst)[i] = o;
}

// ---------------- QKV projection GEMM (R4 structure, unchanged) ----------------
__global__ __launch_bounds__(256)
void qkv_gemm(const bf16_t* __restrict__ X, const bf16_t* __restrict__ Wb,
              const float* __restrict__ bq, const float* __restrict__ bk,
              const float* __restrict__ bv,
              bf16_t* __restrict__ Qo, bf16_t* __restrict__ Ko, bf16_t* __restrict__ Vo)
{
  __shared__ __align__(16) bf16_t smem[17408];  // staging 4x4096; epilogue 128x136
  bf16_t* const sA0 = smem;
  bf16_t* const sA1 = smem + 4096;
  bf16_t* const sB0 = smem + 8192;
  bf16_t* const sB1 = smem + 12288;
  bf16_t* const ep  = smem;

  const int tid = threadIdx.x;
  const int lane = tid & 63, w = tid >> 6;
  const int wr = w >> 1, wc = w & 1;
  const int lq = lane & 15, lg = lane >> 4;
  const int m0 = blockIdx.x * 128;
  const int n0 = blockIdx.y * 128;
  const int z  = blockIdx.z;

  const bf16_t* W = Wb + z * 589824;
  const float* bias = (z == 0) ? bq : (z == 1) ? bk : bv;

  const int arow = wr * 64, brow = wc * 64;
  const int sr = tid >> 2, scc = (tid & 3) * 8;

  const bf16_t* gA = X + (m0 + sr) * 768 + scc;       // +64*768 for j=1
  const bf16_t* gB = W + (n0 + sr) * 768 + scc;
  const int ko = lg * 8;

  f32x4 acc[4][4] = {};

#define STAGE(bufA, bufB, kt)                                            \
  do {                                                                   \
    const int kk_ = (kt) * 32;                                           \
    gload_lds16(gA + kk_,             &bufA[tid * 8]);                   \
    gload_lds16(gA + kk_ + 64 * 768,  &bufA[(tid + 256) * 8]);           \
    gload_lds16(gB + kk_,             &bufB[tid * 8]);                   \
    gload_lds16(gB + kk_ + 64 * 768,  &bufB[(tid + 256) * 8]);           \
  } while (0)

#define COMPUTE(bufA, bufB)                                              \
  do {                                                                   \
    bf16x8 af[4], bfr[4];                                                \
    _Pragma("unroll")                                                    \
    for (int mf = 0; mf < 4; ++mf)                                       \
      af[mf] = *(const bf16x8*)&bufA[(arow + mf * 16 + lq) * 32 + ko];   \
    _Pragma("unroll")                                                    \
    for (int nf = 0; nf < 4; ++nf)                                       \
      bfr[nf] = *(const bf16x8*)&bufB[(brow + nf * 16 + lq) * 32 + ko];  \
    _Pragma("unroll")                                                    \
    for (int mf = 0; mf < 4; ++mf)                                       \
      _Pragma("unroll")                                                  \
      for (int nf = 0; nf < 4; ++nf)                                     \
        acc[mf][nf] = MFMA(af[mf], bfr[nf], acc[mf][nf]);                \
  } while (0)

  STAGE(sA0, sB0, 0);
  for (int kt = 0; kt < 24; kt += 2) {
    __syncthreads();                      // buf0 staged; prior buf1 reads done
    STAGE(sA1, sB1, kt + 1);              // async, drains at next barrier
    COMPUTE(sA0, sB0);
    __syncthreads();                      // buf1 staged; buf0 reads done
    if (kt + 2 < 24) STAGE(sA0, sB0, kt + 2);
    COMPUTE(sA1, sB1);
  }
  __syncthreads();  // last ds_reads done before epilogue overwrites smem

  // ---- epilogue: repack through LDS for coalesced global writes ----
  const int b = m0 >> 10, sq0 = m0 & 1023;

  if (z < 2) {
#pragma unroll
    for (int nf = 0; nf < 4; ++nf) {
      const int c = brow + nf * 16 + lq;
      const float bval = bias[n0 + c];
#pragma unroll
      for (int mf = 0; mf < 4; ++mf)
#pragma unroll
        for (int jr = 0; jr < 4; ++jr)
          ep[(arow + mf * 16 + lg * 4 + jr) * 136 + c] = (bf16_t)(acc[mf][nf][jr] + bval);
    }
    __syncthreads();
    bf16_t* dst = (z == 0) ? Qo : Ko;
#pragma unroll
    for (int nh = 0; nh < 2; ++nh) {
      const int h = (n0 >> 6) + nh;
#pragma unroll
      for (int rp = 0; rp < 2; ++rp) {
        const int r = (tid >> 2) + rp * 64;
        bf16_t* o = dst + ((size_t)(b * 12 + h) * 1024 + sq0 + r) * 64;
        const bf16_t* s = &ep[r * 136 + nh * 64];
#pragma unroll
        for (int i = 0; i < 2; ++i) {
          const int ch = (tid & 3) + i * 4;
          *(bf16x8*)(o + ch * 8) = *(const bf16x8*)(s + ch * 8);
        }
      }
    }
  } else {
    // transposed: ep[c][r] so V^T rows (fixed d, varying s) are contiguous
#pragma unroll
    for (int nf = 0; nf < 4; ++nf) {
      const int c = brow + nf * 16 + lq;
      const float bval = bias[n0 + c];
#pragma unroll
      for (int mf = 0; mf < 4; ++mf) {
        const int r0 = arow + mf * 16 + lg * 4;
        bf16x4 pv = { (bf16_t)(acc[mf][nf][0] + bval), (bf16_t)(acc[mf][nf][1] + bval),
                      (bf16_t)(acc[mf][nf][2] + bval), (bf16_t)(acc[mf][nf][3] + bval) };
        *(bf16x4*)&ep[c * 136 + r0] = pv;
      }
    }
    __syncthreads();
    const int c = tid >> 1;
    const int h = (n0 >> 6) + (c >> 6), dd = c & 63;
    bf16_t* o = Vo + ((size_t)(b * 12 + h) * 64 + dd) * 1024 + sq0;
    const bf16_t* s = &ep[c * 136];
#pragma unroll
    for (int i = 0; i < 8; ++i) {
      const int ch = (tid & 1) + i * 2;
      *(bf16x8*)(o + ch * 8) = *(const bf16x8*)(s + ch * 8);
    }
  }
#undef STAGE
#undef COMPUTE
}

// ---------------- fused attention v8: R11 structure, 8 waves (512 thr) ----------------
// grid (96, 32): x = head (XCD-pinned), y = 32-row q-block. LDS ~71 KB -> 2 blocks/CU,
// now 16 waves/CU (4/SIMD). Phase 1: wave w does t-chunks (w+8i)*64, i<2.
// Phase 2: wave w -> d-range (w&3)*16, ks-half (w>>2); partials combined via LDS.
__global__ __launch_bounds__(512)
void attn_kernel(const bf16_t* __restrict__ Q, const bf16_t* __restrict__ K,
                 const bf16_t* __restrict__ V, float* __restrict__ out,
                 float* __restrict__ Aout)
{
  __shared__ __align__(16) bf16_t Pl[32 * 1032];  // 32 q-rows x 1024 t (+8 pad)
  __shared__ __align__(16) bf16_t Ql[32 * 72];
  __shared__ float red[8][32];
  __shared__ float inv_s[32];

  const int tid = threadIdx.x, lane = tid & 63, w = tid >> 6;
  const int lq = lane & 15, lg = lane >> 4;
  const int bh = blockIdx.x, q0 = blockIdx.y * 32;

  const bf16_t* Qp = Q + (bh * 1024 + q0) * 64;
  const bf16_t* Kp = K + bh * 1024 * 64;
  const bf16_t* Vt = V + bh * 64 * 1024;

  if (tid < 256) {  // load Q block 32x64
    const int q = tid >> 3, du = (tid & 7) * 8;
    *(bf16x8*)&Ql[q * 72 + du] = *(const bf16x8*)(Qp + q * 64 + du);
  }
  __syncthreads();

  const float CEXP = 1.4426950408889634f / 27.712812921102035f;  // log2(e)/sqrt(768)

  bf16x8 bqf[2][2];
#pragma unroll
  for (int dh = 0; dh < 2; ++dh)
#pragma unroll
    for (int qf = 0; qf < 2; ++qf)
      bqf[dh][qf] = *(const bf16x8*)&Ql[(qf * 16 + lq) * 72 + dh * 32 + lg * 8];

  float psum0 = 0.f, psum1 = 0.f;

  for (int i = 0; i < 2; ++i) {
    const int t0 = (w + i * 8) * 64;
    bf16x8 af[4][2];
#pragma unroll
    for (int mf = 0; mf < 4; ++mf) {
      const bf16_t* kp = Kp + (t0 + mf * 16 + lq) * 64 + lg * 8;
      af[mf][0] = *(const bf16x8*)(kp);
      af[mf][1] = *(const bf16x8*)(kp + 32);
    }
#pragma unroll
    for (int mf = 0; mf < 4; ++mf) {
#pragma unroll
      for (int qf = 0; qf < 2; ++qf) {
        f32x4 acc = {};
        acc = MFMA(af[mf][0], bqf[0][qf], acc);
        acc = MFMA(af[mf][1], bqf[1][qf], acc);
        float p0 = exp2f(acc[0] * CEXP);
        float p1 = exp2f(acc[1] * CEXP);
        float p2 = exp2f(acc[2] * CEXP);
        float p3 = exp2f(acc[3] * CEXP);
        if (qf == 0) psum0 += p0 + p1 + p2 + p3;
        else         psum1 += p0 + p1 + p2 + p3;
        bf16x4 pv = { (bf16_t)p0, (bf16_t)p1, (bf16_t)p2, (bf16_t)p3 };
        const int q = qf * 16 + lq;
        const int tt = t0 + mf * 16 + lg * 4;
        *(bf16x4*)&Pl[q * 1032 + tt] = pv;
      }
    }
  }

  psum0 += __shfl_xor(psum0, 16); psum0 += __shfl_xor(psum0, 32);
  psum1 += __shfl_xor(psum1, 16); psum1 += __shfl_xor(psum1, 32);
  if (lane < 16) { red[w][lane] = psum0; red[w][16 + lane] = psum1; }
  __syncthreads();
  if (tid < 32) {
    float s = 0.f;
#pragma unroll
    for (int j = 0; j < 8; ++j) s += red[j][tid];
    inv_s[tid] = 1.0f / s;
  }
  __syncthreads();

  // ---- phase 2: PV (split ks) + fused A-store (1 KB contiguous per wave instr) ----
  const int dq = w & 3, kh = w >> 2;     // d-range, ks-half
  const int r4 = 4 * w;                  // A-store rows 4w..4w+3
  float* const Ap0 = Aout + ((size_t)bh * 1024 + q0) * 1024;

  f32x4 oacc[2] = {};
  for (int ks = 0; ks < 16; ++ks) {
    const int kc = (kh * 16 + ks) * 32;
    bf16x8 vb = *(const bf16x8*)(Vt + (dq * 16 + lq) * 1024 + kc + lg * 8);
#pragma unroll
    for (int mf = 0; mf < 2; ++mf) {
      bf16x8 pa = *(const bf16x8*)&Pl[(mf * 16 + lq) * 1032 + kc + lg * 8];
      oacc[mf] = MFMA(pa, vb, oacc[mf]);
    }
    const int ar = r4 + (ks & 3);        // wave-uniform row
    const int cc = (ks >> 2) * 256;      // wave-uniform 1KB chunk
    const float ainv = inv_s[ar];        // LDS broadcast
    bf16x4 pv = *(const bf16x4*)&Pl[ar * 1032 + cc + lane * 4];
    f32x4 o = { (float)pv[0] * ainv, (float)pv[1] * ainv,
                (float)pv[2] * ainv, (float)pv[3] * ainv };
    __builtin_nontemporal_store(o, (f32x4*)(Ap0 + (size_t)ar * 1024 + cc + lane * 4));
  }

  // ---- combine ks-halves + out epilogue (256B contiguous per row) ----
  __syncthreads();                       // all Pl reads complete
  float* const Ol = (float*)Pl;          // reuse as [2][32][68] f32 (17.4 KB)
#pragma unroll
  for (int mf = 0; mf < 2; ++mf)
#pragma unroll
    for (int jr = 0; jr < 4; ++jr) {
      const int q = mf * 16 + lg * 4 + jr;
      Ol[kh * 2176 + q * 68 + dq * 16 + lq] = oacc[mf][jr];
    }
  __syncthreads();
  {
    const int b = bh / 12, h = bh % 12;
    const int r = tid >> 4, c4 = (tid & 15) * 4;
    const float s = inv_s[r];
    f32x4 p0 = *(const f32x4*)&Ol[r * 68 + c4];
    f32x4 p1 = *(const f32x4*)&Ol[2176 + r * 68 + c4];
    f32x4 o = { (p0[0] + p1[0]) * s, (p0[1] + p1[1]) * s,
                (p0[2] + p1[2]) * s, (p0[3] + p1[3]) * s };
    *(f32x4*)(out + ((size_t)b * 1024 + q0 + r) * 768 + h * 64 + c4) = o;
  }
}

extern "C" void kernel_launch(void* const* d_in, const int* in_sizes, int n_in,
                              void* d_out, int out_size, void* d_ws, size_t ws_size,
                              hipStream_t stream) {
  (void)in_sizes; (void)n_in; (void)out_size; (void)ws_size;
  const float* x  = (const float*)d_in[0];
  const float* Wq = (const float*)d_in[1];
  const float* bq = (const float*)d_in[2];
  const float* Wk = (const float*)d_in[3];
  const float* bk = (const float*)d_in[4];
  const float* Wv = (const float*)d_in[5];
  const float* bv = (const float*)d_in[6];

  float* out  = (float*)d_out;
  float* Aout = out + 6291456;  // out [8,1024,768]; A follows

  // workspace (bf16 elements): x_bf | wq|wk|wv | q | k | v^T
  bf16_t* ws   = (bf16_t*)d_ws;
  bf16_t* x_bf = ws;
  bf16_t* w_bf = ws + 6291456;
  bf16_t* q_ws = ws + 8060928;
  bf16_t* k_ws = ws + 14352384;
  bf16_t* v_ws = ws + 20643840;

  cvt_all<<<7872, 256, 0, stream>>>(x, Wq, Wk, Wv, ws);
  qkv_gemm<<<dim3(64, 6, 3), 256, 0, stream>>>(x_bf, w_bf, bq, bk, bv, q_ws, k_ws, v_ws);
  attn_kernel<<<dim3(96, 32), 512, 0, stream>>>(q_ws, k_ws, v_ws, out, Aout);
}

// Round 16
// 169.976 us; speedup vs baseline: 6.3067x; 1.0024x over previous
//
#include <hip/hip_runtime.h>
#include <stdint.h>

typedef __bf16 bf16_t;
typedef __bf16 bf16x4 __attribute__((ext_vector_type(4)));
typedef __bf16 bf16x8 __attribute__((ext_vector_type(8)));
typedef float f32x4 __attribute__((ext_vector_type(4)));

#define MFMA(a, b, c) __builtin_amdgcn_mfma_f32_16x16x32_bf16(a, b, c, 0, 0, 0)

// raw v_exp_f32 — single HW instruction; inputs here are bounded (|x| < 6)
__device__ __forceinline__ float fexp2(float x) { return __builtin_amdgcn_exp2f(x); }

// async global->LDS, 16B per lane; LDS dest = wave-uniform base + lane*16
typedef __attribute__((address_space(3))) uint32_t as3_u32;
typedef __attribute__((address_space(1))) uint32_t as1_u32;
__device__ __forceinline__ void gload_lds16(const void* g, void* l) {
  __builtin_amdgcn_global_load_lds((as1_u32*)g, (as3_u32*)l, 16, 0, 0);
}

// ---------------- f32 -> bf16 convert, all inputs fused ----------------
__global__ void cvt_all(const float* __restrict__ x, const float* __restrict__ wq,
                        const float* __restrict__ wk, const float* __restrict__ wv,
                        bf16_t* __restrict__ dst) {
  int i = blockIdx.x * blockDim.x + threadIdx.x;
  if (i >= 2015232) return;
  const float* src; int off;
  if (i < 1572864) { src = x; off = i; }
  else {
    int j = i - 1572864;
    if (j < 147456)      { src = wq; off = j; }
    else if (j < 294912) { src = wk; off = j - 147456; }
    else                 { src = wv; off = j - 294912; }
  }
  const f32x4 v = reinterpret_cast<const f32x4*>(src)[off];
  bf16x4 o = { (bf16_t)v.x, (bf16_t)v.y, (bf16_t)v.z, (bf16_t)v.w };
  reinterpret_cast<bf16x4*>(dst)[i] = o;
}

// ---------------- QKV projection GEMM (R4 structure, unchanged) ----------------
__global__ __launch_bounds__(256)
void qkv_gemm(const bf16_t* __restrict__ X, const bf16_t* __restrict__ Wb,
              const float* __restrict__ bq, const float* __restrict__ bk,
              const float* __restrict__ bv,
              bf16_t* __restrict__ Qo, bf16_t* __restrict__ Ko, bf16_t* __restrict__ Vo)
{
  __shared__ __align__(16) bf16_t smem[17408];  // staging 4x4096; epilogue 128x136
  bf16_t* const sA0 = smem;
  bf16_t* const sA1 = smem + 4096;
  bf16_t* const sB0 = smem + 8192;
  bf16_t* const sB1 = smem + 12288;
  bf16_t* const ep  = smem;

  const int tid = threadIdx.x;
  const int lane = tid & 63, w = tid >> 6;
  const int wr = w >> 1, wc = w & 1;
  const int lq = lane & 15, lg = lane >> 4;
  const int m0 = blockIdx.x * 128;
  const int n0 = blockIdx.y * 128;
  const int z  = blockIdx.z;

  const bf16_t* W = Wb + z * 589824;
  const float* bias = (z == 0) ? bq : (z == 1) ? bk : bv;

  const int arow = wr * 64, brow = wc * 64;
  const int sr = tid >> 2, scc = (tid & 3) * 8;

  const bf16_t* gA = X + (m0 + sr) * 768 + scc;       // +64*768 for j=1
  const bf16_t* gB = W + (n0 + sr) * 768 + scc;
  const int ko = lg * 8;

  f32x4 acc[4][4] = {};

#define STAGE(bufA, bufB, kt)                                            \
  do {                                                                   \
    const int kk_ = (kt) * 32;                                           \
    gload_lds16(gA + kk_,             &bufA[tid * 8]);                   \
    gload_lds16(gA + kk_ + 64 * 768,  &bufA[(tid + 256) * 8]);           \
    gload_lds16(gB + kk_,             &bufB[tid * 8]);                   \
    gload_lds16(gB + kk_ + 64 * 768,  &bufB[(tid + 256) * 8]);           \
  } while (0)

#define COMPUTE(bufA, bufB)                                              \
  do {                                                                   \
    bf16x8 af[4], bfr[4];                                                \
    _Pragma("unroll")                                                    \
    for (int mf = 0; mf < 4; ++mf)                                       \
      af[mf] = *(const bf16x8*)&bufA[(arow + mf * 16 + lq) * 32 + ko];   \
    _Pragma("unroll")                                                    \
    for (int nf = 0; nf < 4; ++nf)                                       \
      bfr[nf] = *(const bf16x8*)&bufB[(brow + nf * 16 + lq) * 32 + ko];  \
    _Pragma("unroll")                                                    \
    for (int mf = 0; mf < 4; ++mf)                                       \
      _Pragma("unroll")                                                  \
      for (int nf = 0; nf < 4; ++nf)                                     \
        acc[mf][nf] = MFMA(af[mf], bfr[nf], acc[mf][nf]);                \
  } while (0)

  STAGE(sA0, sB0, 0);
  for (int kt = 0; kt < 24; kt += 2) {
    __syncthreads();                      // buf0 staged; prior buf1 reads done
    STAGE(sA1, sB1, kt + 1);              // async, drains at next barrier
    COMPUTE(sA0, sB0);
    __syncthreads();                      // buf1 staged; buf0 reads done
    if (kt + 2 < 24) STAGE(sA0, sB0, kt + 2);
    COMPUTE(sA1, sB1);
  }
  __syncthreads();  // last ds_reads done before epilogue overwrites smem

  // ---- epilogue: repack through LDS for coalesced global writes ----
  const int b = m0 >> 10, sq0 = m0 & 1023;

  if (z < 2) {
#pragma unroll
    for (int nf = 0; nf < 4; ++nf) {
      const int c = brow + nf * 16 + lq;
      const float bval = bias[n0 + c];
#pragma unroll
      for (int mf = 0; mf < 4; ++mf)
#pragma unroll
        for (int jr = 0; jr < 4; ++jr)
          ep[(arow + mf * 16 + lg * 4 + jr) * 136 + c] = (bf16_t)(acc[mf][nf][jr] + bval);
    }
    __syncthreads();
    bf16_t* dst = (z == 0) ? Qo : Ko;
#pragma unroll
    for (int nh = 0; nh < 2; ++nh) {
      const int h = (n0 >> 6) + nh;
#pragma unroll
      for (int rp = 0; rp < 2; ++rp) {
        const int r = (tid >> 2) + rp * 64;
        bf16_t* o = dst + ((size_t)(b * 12 + h) * 1024 + sq0 + r) * 64;
        const bf16_t* s = &ep[r * 136 + nh * 64];
#pragma unroll
        for (int i = 0; i < 2; ++i) {
          const int ch = (tid & 3) + i * 4;
          *(bf16x8*)(o + ch * 8) = *(const bf16x8*)(s + ch * 8);
        }
      }
    }
  } else {
    // transposed: ep[c][r] so V^T rows (fixed d, varying s) are contiguous
#pragma unroll
    for (int nf = 0; nf < 4; ++nf) {
      const int c = brow + nf * 16 + lq;
      const float bval = bias[n0 + c];
#pragma unroll
      for (int mf = 0; mf < 4; ++mf) {
        const int r0 = arow + mf * 16 + lg * 4;
        bf16x4 pv = { (bf16_t)(acc[mf][nf][0] + bval), (bf16_t)(acc[mf][nf][1] + bval),
                      (bf16_t)(acc[mf][nf][2] + bval), (bf16_t)(acc[mf][nf][3] + bval) };
        *(bf16x4*)&ep[c * 136 + r0] = pv;
      }
    }
    __syncthreads();
    const int c = tid >> 1;
    const int h = (n0 >> 6) + (c >> 6), dd = c & 63;
    bf16_t* o = Vo + ((size_t)(b * 12 + h) * 64 + dd) * 1024 + sq0;
    const bf16_t* s = &ep[c * 136];
#pragma unroll
    for (int i = 0; i < 8; ++i) {
      const int ch = (tid & 1) + i * 2;
      *(bf16x8*)(o + ch * 8) = *(const bf16x8*)(s + ch * 8);
    }
  }
#undef STAGE
#undef COMPUTE
}

// ---------------- fused attention v9: R15 8-wave structure + raw v_exp_f32 ----------------
// grid (96, 32): x = head (XCD-pinned), y = 32-row q-block. 512 threads, LDS ~71 KB.
__global__ __launch_bounds__(512)
void attn_kernel(const bf16_t* __restrict__ Q, const bf16_t* __restrict__ K,
                 const bf16_t* __restrict__ V, float* __restrict__ out,
                 float* __restrict__ Aout)
{
  __shared__ __align__(16) bf16_t Pl[32 * 1032];  // 32 q-rows x 1024 t (+8 pad)
  __shared__ __align__(16) bf16_t Ql[32 * 72];
  __shared__ float red[8][32];
  __shared__ float inv_s[32];

  const int tid = threadIdx.x, lane = tid & 63, w = tid >> 6;
  const int lq = lane & 15, lg = lane >> 4;
  const int bh = blockIdx.x, q0 = blockIdx.y * 32;

  const bf16_t* Qp = Q + (bh * 1024 + q0) * 64;
  const bf16_t* Kp = K + bh * 1024 * 64;
  const bf16_t* Vt = V + bh * 64 * 1024;

  if (tid < 256) {  // load Q block 32x64
    const int q = tid >> 3, du = (tid & 7) * 8;
    *(bf16x8*)&Ql[q * 72 + du] = *(const bf16x8*)(Qp + q * 64 + du);
  }
  __syncthreads();

  const float CEXP = 1.4426950408889634f / 27.712812921102035f;  // log2(e)/sqrt(768)

  bf16x8 bqf[2][2];
#pragma unroll
  for (int dh = 0; dh < 2; ++dh)
#pragma unroll
    for (int qf = 0; qf < 2; ++qf)
      bqf[dh][qf] = *(const bf16x8*)&Ql[(qf * 16 + lq) * 72 + dh * 32 + lg * 8];

  float psum0 = 0.f, psum1 = 0.f;

  for (int i = 0; i < 2; ++i) {
    const int t0 = (w + i * 8) * 64;
    bf16x8 af[4][2];
#pragma unroll
    for (int mf = 0; mf < 4; ++mf) {
      const bf16_t* kp = Kp + (t0 + mf * 16 + lq) * 64 + lg * 8;
      af[mf][0] = *(const bf16x8*)(kp);
      af[mf][1] = *(const bf16x8*)(kp + 32);
    }
#pragma unroll
    for (int mf = 0; mf < 4; ++mf) {
#pragma unroll
      for (int qf = 0; qf < 2; ++qf) {
        f32x4 acc = {};
        acc = MFMA(af[mf][0], bqf[0][qf], acc);
        acc = MFMA(af[mf][1], bqf[1][qf], acc);
        float p0 = fexp2(acc[0] * CEXP);
        float p1 = fexp2(acc[1] * CEXP);
        float p2 = fexp2(acc[2] * CEXP);
        float p3 = fexp2(acc[3] * CEXP);
        if (qf == 0) psum0 += p0 + p1 + p2 + p3;
        else         psum1 += p0 + p1 + p2 + p3;
        bf16x4 pv = { (bf16_t)p0, (bf16_t)p1, (bf16_t)p2, (bf16_t)p3 };
        const int q = qf * 16 + lq;
        const int tt = t0 + mf * 16 + lg * 4;
        *(bf16x4*)&Pl[q * 1032 + tt] = pv;
      }
    }
  }

  psum0 += __shfl_xor(psum0, 16); psum0 += __shfl_xor(psum0, 32);
  psum1 += __shfl_xor(psum1, 16); psum1 += __shfl_xor(psum1, 32);
  if (lane < 16) { red[w][lane] = psum0; red[w][16 + lane] = psum1; }
  __syncthreads();
  if (tid < 32) {
    float s = 0.f;
#pragma unroll
    for (int j = 0; j < 8; ++j) s += red[j][tid];
    inv_s[tid] = 1.0f / s;
  }
  __syncthreads();

  // ---- phase 2: PV (split ks) + fused A-store (1 KB contiguous per wave instr) ----
  const int dq = w & 3, kh = w >> 2;     // d-range, ks-half
  const int r4 = 4 * w;                  // A-store rows 4w..4w+3
  float* const Ap0 = Aout + ((size_t)bh * 1024 + q0) * 1024;

  f32x4 oacc[2] = {};
  for (int ks = 0; ks < 16; ++ks) {
    const int kc = (kh * 16 + ks) * 32;
    bf16x8 vb = *(const bf16x8*)(Vt + (dq * 16 + lq) * 1024 + kc + lg * 8);
#pragma unroll
    for (int mf = 0; mf < 2; ++mf) {
      bf16x8 pa = *(const bf16x8*)&Pl[(mf * 16 + lq) * 1032 + kc + lg * 8];
      oacc[mf] = MFMA(pa, vb, oacc[mf]);
    }
    const int ar = r4 + (ks & 3);        // wave-uniform row
    const int cc = (ks >> 2) * 256;      // wave-uniform 1KB chunk
    const float ainv = inv_s[ar];        // LDS broadcast
    bf16x4 pv = *(const bf16x4*)&Pl[ar * 1032 + cc + lane * 4];
    f32x4 o = { (float)pv[0] * ainv, (float)pv[1] * ainv,
                (float)pv[2] * ainv, (float)pv[3] * ainv };
    __builtin_nontemporal_store(o, (f32x4*)(Ap0 + (size_t)ar * 1024 + cc + lane * 4));
  }

  // ---- combine ks-halves + out epilogue (256B contiguous per row) ----
  __syncthreads();                       // all Pl reads complete
  float* const Ol = (float*)Pl;          // reuse as [2][32][68] f32 (17.4 KB)
#pragma unroll
  for (int mf = 0; mf < 2; ++mf)
#pragma unroll
    for (int jr = 0; jr < 4; ++jr) {
      const int q = mf * 16 + lg * 4 + jr;
      Ol[kh * 2176 + q * 68 + dq * 16 + lq] = oacc[mf][jr];
    }
  __syncthreads();
  {
    const int b = bh / 12, h = bh % 12;
    const int r = tid >> 4, c4 = (tid & 15) * 4;
    const float s = inv_s[r];
    f32x4 p0 = *(const f32x4*)&Ol[r * 68 + c4];
    f32x4 p1 = *(const f32x4*)&Ol[2176 + r * 68 + c4];
    f32x4 o = { (p0[0] + p1[0]) * s, (p0[1] + p1[1]) * s,
                (p0[2] + p1[2]) * s, (p0[3] + p1[3]) * s };
    *(f32x4*)(out + ((size_t)b * 1024 + q0 + r) * 768 + h * 64 + c4) = o;
  }
}

extern "C" void kernel_launch(void* const* d_in, const int* in_sizes, int n_in,
                              void* d_out, int out_size, void* d_ws, size_t ws_size,
                              hipStream_t stream) {
  (void)in_sizes; (void)n_in; (void)out_size; (void)ws_size;
  const float* x  = (const float*)d_in[0];
  const float* Wq = (const float*)d_in[1];
  const float* bq = (const float*)d_in[2];
  const float* Wk = (const float*)d_in[3];
  const float* bk = (const float*)d_in[4];
  const float* Wv = (const float*)d_in[5];
  const float* bv = (const float*)d_in[6];

  float* out  = (float*)d_out;
  float* Aout = out + 6291456;  // out [8,1024,768]; A follows

  // workspace (bf16 elements): x_bf | wq|wk|wv | q | k | v^T
  bf16_t* ws   = (bf16_t*)d_ws;
  bf16_t* x_bf = ws;
  bf16_t* w_bf = ws + 6291456;
  bf16_t* q_ws = ws + 8060928;
  bf16_t* k_ws = ws + 14352384;
  bf16_t* v_ws = ws + 20643840;

  cvt_all<<<7872, 256, 0, stream>>>(x, Wq, Wk, Wv, ws);
  qkv_gemm<<<dim3(64, 6, 3), 256, 0, stream>>>(x_bf, w_bf, bq, bk, bv, q_ws, k_ws, v_ws);
  attn_kernel<<<dim3(96, 32), 512, 0, stream>>>(q_ws, k_ws, v_ws, out, Aout);
}